// Round 3
// baseline (2277.440 us; speedup 1.0000x reference)
//
#include <hip/hip_runtime.h>

// DTW accumulated-cost, output = last column. N=65536 rows (input), K=512 cols (kernel).
// Anti-diagonal recurrence with E[j]=min(A_t[j],A_{t-1}[j]):
//   A_{t+1}[j] = min(A_t[j], E_t[j-1]) + (k[j]-x[i])^2 ,  i = t+1-j
// 4 waves (one per SIMD) split j into 128-wide bands (j = 128w + 2*lane + slot);
// skewed-chunk barrier pipeline passes band-boundary E values through LDS rings.
// R3: fully systolic inner loop — x values, boundary-in, and boundary/output-out
// all flow through rotating DPP registers (wave_shr:1 / wave_shl:1). The 64-diag
// inner loop is pure VALU: 1 coalesced global load + 1 ds_read + 1 write PER CHUNK.
// R2's 76 cyc/diag was ~50 cyc of vmcnt/lgkmcnt stalls from compiler-sunk loads.

#define K_LEN 512
#define N_LEN 65536
#define PAD_L 512
#define PAD_R 1024
#define XPAD_TOTAL (PAD_L + N_LEN + PAD_R) // 67072 floats = 268288 B of d_ws
#define BIGX 1e20f
#define NCHUNK 1032                        // 1032*64 = 66048 >= N+K-1 = 66047 diagonals
#define RING 256                           // ring entries per boundary buffer (4 chunks)

// wave_shr:1 = 0x138 (out[l] = in[l-1]; lane 0 <- old[0])   [verified R1/R2: passed]
// wave_shl:1 = 0x130 (out[l] = in[l+1]; lane 63 <- old[63])
#define DPPF(old, src, ctrl)                                                     \
    __int_as_float(__builtin_amdgcn_update_dpp(                                  \
        __float_as_int(old), __float_as_int(src), (ctrl), 0xF, 0xF, false))

__global__ void dtw_pad_kernel(const float* __restrict__ x, float* __restrict__ xpad) {
    int i = blockIdx.x * blockDim.x + threadIdx.x;
    if (i < XPAD_TOTAL) {
        int j = i - PAD_L;
        xpad[i] = (j >= 0 && j < N_LEN) ? x[j] : BIGX;
    }
}

template <bool LAST>
__device__ __forceinline__ void dtw_chunk(int c, float& Xa, const float* __restrict__ xlw,
                                          const float* __restrict__ ldsIn,
                                          float* __restrict__ ldsOut,
                                          float k0, float k1,
                                          float& A0, float& A1, float& E0, float& E1,
                                          float& xA, float& xB, int lane,
                                          float* __restrict__ out) {
    const int t0 = c * 64;
    const int rb = (c & 3) * 64;

    // Prefetch NEXT chunk's x-injection stream (xpad is constant — no barrier dep,
    // so this load has a full chunk (~1500 cyc) to complete: zero stall).
    const float Xb = xlw[t0 + 64 + lane];

    // Boundary stream: lane r holds E_{t0+r-1}[jbase-1]. One ds_read, stride-1
    // (2-way bank aliasing = free). Written by neighbor wave before last barrier.
    float B = ldsIn[(rb + lane + RING - 1) & (RING - 1)];

    float X = Xa;     // rotating injection register (lane 0 element consumed per iter)
    float C = 0.0f;   // rotating collector (lane 63 element inserted per iter)

#pragma unroll
    for (int r = 0; r < 64; ++r) {
        // slot-0 fresh x: lane l <- lane l-1's x(t-2); lane 0 <- X[0] (dpp old)
        const float xnew = DPPF(X, xB, 0x138);
        // slot-0 shifted E: lane l <- lane l-1's E1; lane 0 <- B[0] (dpp old)
        const float esh0 = DPPF(B, E1, 0x138);
        X = DPPF(X, X, 0x130); // rotate injection stream down one lane
        B = DPPF(B, B, 0x130); // rotate boundary stream down one lane
        float d0 = k0 - xnew; d0 *= d0;
        float d1 = k1 - xA;   d1 *= d1;
        const float na0 = fminf(A0, esh0) + d0;
        const float na1 = fminf(A1, E0) + d1;   // esh1 = E0 (same-lane neighbor)
        const float ne0 = fminf(na0, A0);
        const float ne1 = fminf(na1, A1);
        // collect lane 63's boundary E (waves 0-2) / output A[511] (wave 3):
        // insert at lane 63, shift down; after 64 iters lane r holds iter r's value
        C = DPPF(LAST ? na1 : ne1, C, 0x130);
        A0 = na0; A1 = na1; E0 = ne0; E1 = ne1;
        xB = xA; xA = xnew;
    }

    Xa = Xb;
    if (!LAST) {
        ldsOut[rb + lane] = C;                 // one full-wave ds_write per chunk
    } else {
        const int oi = t0 + lane - (K_LEN - 1);
        if (oi >= 0 && oi < N_LEN) out[oi] = C; // direct coalesced store, no staging
    }
}

__global__ __launch_bounds__(256, 1) void dtw_main(const float* __restrict__ xpad,
                                                   const float* __restrict__ kern,
                                                   float* __restrict__ out) {
    __shared__ float lds[5 * RING]; // buf[w]=w*RING written by wave w (buf3 unused),
                                    // INIT buffer at 4*RING read by wave 0
    const float INFV = __builtin_inff();
    const int tid  = threadIdx.x;
    const int w    = __builtin_amdgcn_readfirstlane(tid) >> 6; // wave id, uniform SGPR
    const int lane = tid & 63;

    // LDS init: all INF; INIT[255] = 0.0 is the DP seed ac[-1][-1]=0 (read by wave 0 at t=0)
    for (int i = tid; i < 5 * RING; i += 256)
        lds[i] = (i == 4 * RING + RING - 1) ? 0.0f : INFV;
    __syncthreads();

    const int j0 = w * 128 + 2 * lane;      // slot-0 column; slot-1 = j0+1
    const float k0 = kern[j0];
    const float k1 = kern[j0 + 1];

    const float* xl  = xpad + PAD_L - j0;   // per-lane stream (init only)
    const float* xlw = xpad + PAD_L - w * 128; // lane-0 (wave-uniform) stream base
    float xA = xl[-1];                      // x(t-1) pipeline reg
    float xB = xl[-2];                      // x(t-2) pipeline reg
    float Xa = xlw[lane];                   // chunk 0 injection stream

    float* ldsOut      = lds + w * RING;
    const float* ldsIn = (w == 0) ? (lds + 4 * RING) : (lds + (w - 1) * RING);

    float A0 = INFV, A1 = INFV, E0 = INFV, E1 = INFV;

    for (int S = 0; S < NCHUNK + 3; ++S) {
        const int c = S - w;                // chunk index for this wave (skewed pipeline)
        if (c >= 0 && c < NCHUNK) {
            if (w == 3)
                dtw_chunk<true>(c, Xa, xlw, ldsIn, ldsOut, k0, k1, A0, A1, E0, E1, xA, xB, lane, out);
            else
                dtw_chunk<false>(c, Xa, xlw, ldsIn, ldsOut, k0, k1, A0, A1, E0, E1, xA, xB, lane, out);
        }
        if (S == 0 && tid == 0) lds[4 * RING + RING - 1] = INFV; // retire the seed before ring wraps
        __syncthreads();
    }
}

extern "C" void kernel_launch(void* const* d_in, const int* in_sizes, int n_in,
                              void* d_out, int out_size, void* d_ws, size_t ws_size,
                              hipStream_t stream) {
    const float* x = (const float*)d_in[0];   // input, 65536 fp32
    const float* k = (const float*)d_in[1];   // kernel, 512 fp32
    float* xpad = (float*)d_ws;               // needs 268288 B of scratch
    float* out  = (float*)d_out;              // 65536 fp32
    dtw_pad_kernel<<<(XPAD_TOTAL + 255) / 256, 256, 0, stream>>>(x, xpad);
    dtw_main<<<1, 256, 0, stream>>>(xpad, k, out);
}

// Round 5
// 2252.608 us; speedup vs baseline: 1.0110x; 1.0110x over previous
//
#include <hip/hip_runtime.h>

// DTW accumulated-cost, output = last column. N=65536 rows (input), K=512 cols (kernel).
// Anti-diagonal recurrence with E[j]=min(A_t[j],A_{t-1}[j]):
//   A_{t+1}[j] = min(A_t[j], E_t[j-1]) + (k[j]-x[i])^2 ,  i = t+1-j
// 4 waves (one per SIMD) split j into 128-wide bands (j = 128w + 2*lane + slot);
// skewed-chunk barrier pipeline passes band-boundary E values through LDS rings.
// R5: two wave-DPPs per diagonal (E-shift + output collector); boundary inject
// via readlane->cndmask (writelane builtin doesn't exist on this ROCm).
// x from per-lane double-buffered float2 register windows loaded a chunk ahead.
// 13 VALU/diagonal => ~26 cyc issue floor; dep chain ~16 cyc (closes over 2 iters).

#define K_LEN 512
#define N_LEN 65536
#define PAD_L 512
#define PAD_R 1024
#define XPAD_TOTAL (PAD_L + N_LEN + PAD_R) // 67072 floats = 268288 B of d_ws
#define BIGX 1e20f
#define NCHUNK 1032                        // 1032*64 = 66048 >= N+K-1 = 66047 diagonals
#define RING 256                           // ring entries per boundary buffer (4 chunks)

__global__ void dtw_pad_kernel(const float* __restrict__ x, float* __restrict__ xpad) {
    int i = blockIdx.x * blockDim.x + threadIdx.x;
    if (i < XPAD_TOTAL) {
        int j = i - PAD_L;
        xpad[i] = (j >= 0 && j < N_LEN) ? x[j] : BIGX;
    }
}

// One 64-diagonal chunk. xc = this chunk's x window (32 float2 = 64 x values),
// xn gets filled with the NEXT chunk's window (loads issued first, consumed next call).
template <bool LAST>
__device__ __forceinline__ void dtw_chunk(int c, const float* __restrict__ xl,
                                          float2 (&xc)[32], float2 (&xn)[32],
                                          const float* __restrict__ ldsIn,
                                          float* __restrict__ ldsOut,
                                          float k0, float k1,
                                          float& A0, float& A1, float& E0, float& E1,
                                          float& xp, int lane, float* __restrict__ out) {
    const int t0 = c * 64;
    const int rb = (c & 3) * 64;

    // Prefetch next chunk's x window (8B-aligned: float index PAD_L-2*lane+64c+2q is even).
    // Consumed only next chunk -> a full chunk (~1800 cyc) of latency hiding.
    const float2* xnp = reinterpret_cast<const float2*>(xl + t0 + 64);
#pragma unroll
    for (int q = 0; q < 32; ++q) xn[q] = xnp[q];

    // Boundary stream: lane r holds E_{t0+r-1}[jbase-1] (written by the neighbor
    // wave before the last barrier). One full-wave ds_read, consumed via readlane.
    const float B = ldsIn[(rb + lane + RING - 1) & (RING - 1)];

    float C = 0.0f; // collector: after 64 iters lane r holds iter r's lane-63 value

#pragma unroll
    for (int r = 0; r < 64; ++r) {
        const float xf = (r & 1) ? xc[r >> 1].y : xc[r >> 1].x; // slot-0 x this diagonal
        // boundary inject value (wave-uniform SGPR; r is a compile-time constant)
        const int sbi = __builtin_amdgcn_readlane(__float_as_int(B), r);
        // slot-0 shifted E: lane l <- lane l-1's E1 (bound_ctrl=1 -> single mov_dpp)
        const float eshs = __int_as_float(__builtin_amdgcn_update_dpp(
            0, __float_as_int(E1), 0x138 /*wave_shr:1*/, 0xF, 0xF, true));
        // lane 0 <- boundary: v_cndmask with SGPR src + loop-invariant vcc mask
        const float esh0 = (lane != 0) ? eshs : __int_as_float(sbi);

        const float t0c = k0 - xf;
        const float t1c = k1 - xp;
        const float m0  = fminf(A0, esh0);
        const float m1  = fminf(A1, E0);          // slot-1 neighbor is same-lane slot 0
        const float na0 = __builtin_fmaf(t0c, t0c, m0);
        const float na1 = __builtin_fmaf(t1c, t1c, m1);
        const float ne0 = fminf(na0, A0);
        const float ne1 = fminf(na1, A1);

        // collect lane63's boundary E (waves 0-2) / output A[511] (wave 3):
        // rotating DPP collector (verified R3): lane63 <- keepval, rest shift down
        const float keepv = LAST ? na1 : ne1;
        C = __int_as_float(__builtin_amdgcn_update_dpp(
            __float_as_int(keepv), __float_as_int(C), 0x130 /*wave_shl:1*/, 0xF, 0xF, false));

        A0 = na0; A1 = na1; E0 = ne0; E1 = ne1; xp = xf;
    }

    if (!LAST) {
        ldsOut[rb + lane] = C;                  // one full-wave ds_write per chunk
    } else {
        const int oi = t0 + lane - (K_LEN - 1);
        if (oi >= 0 && oi < N_LEN) out[oi] = C; // direct coalesced store
    }
}

__global__ __launch_bounds__(256, 1) void dtw_main(const float* __restrict__ xpad,
                                                   const float* __restrict__ kern,
                                                   float* __restrict__ out) {
    __shared__ float lds[5 * RING]; // buf[w]=w*RING written by wave w (buf3 unused),
                                    // INIT buffer at 4*RING read by wave 0
    const float INFV = __builtin_inff();
    const int tid  = threadIdx.x;
    const int w    = __builtin_amdgcn_readfirstlane(tid) >> 6; // wave id, uniform SGPR
    const int lane = tid & 63;

    // LDS init: all INF; INIT[255] = 0.0 is the DP seed ac[-1][-1]=0 (read by wave 0 at t=0)
    for (int i = tid; i < 5 * RING; i += 256)
        lds[i] = (i == 4 * RING + RING - 1) ? 0.0f : INFV;
    __syncthreads();

    const int j0 = w * 128 + 2 * lane;      // slot-0 column; slot-1 = j0+1
    const float k0 = kern[j0];
    const float k1 = kern[j0 + 1];

    const float* xl = xpad + PAD_L - j0;    // per-lane x stream: slot-0 x at diag t is xl[t]
    float xp = xl[-1];                      // slot-1 x entering t=0 (left pad)

    float* ldsOut      = lds + w * RING;
    const float* ldsIn = (w == 0) ? (lds + 4 * RING) : (lds + (w - 1) * RING);

    float A0 = INFV, A1 = INFV, E0 = INFV, E1 = INFV;

    // x register windows, ping-pong across chunks; preload chunk 0's window
    float2 xwA[32], xwB[32];
    {
        const float2* x0p = reinterpret_cast<const float2*>(xl);
#pragma unroll
        for (int q = 0; q < 32; ++q) xwA[q] = x0p[q];
    }

    for (int S = 0; S < NCHUNK + 3; ++S) {
        const int c = S - w;                // chunk index for this wave (skewed pipeline)
        if (c >= 0 && c < NCHUNK) {
            if (c & 1) {
                if (w == 3) dtw_chunk<true >(c, xl, xwB, xwA, ldsIn, ldsOut, k0, k1, A0, A1, E0, E1, xp, lane, out);
                else        dtw_chunk<false>(c, xl, xwB, xwA, ldsIn, ldsOut, k0, k1, A0, A1, E0, E1, xp, lane, out);
            } else {
                if (w == 3) dtw_chunk<true >(c, xl, xwA, xwB, ldsIn, ldsOut, k0, k1, A0, A1, E0, E1, xp, lane, out);
                else        dtw_chunk<false>(c, xl, xwA, xwB, ldsIn, ldsOut, k0, k1, A0, A1, E0, E1, xp, lane, out);
            }
        }
        if (S == 0 && tid == 0) lds[4 * RING + RING - 1] = INFV; // retire the seed before ring wraps
        __syncthreads();
    }
}

extern "C" void kernel_launch(void* const* d_in, const int* in_sizes, int n_in,
                              void* d_out, int out_size, void* d_ws, size_t ws_size,
                              hipStream_t stream) {
    const float* x = (const float*)d_in[0];   // input, 65536 fp32
    const float* k = (const float*)d_in[1];   // kernel, 512 fp32
    float* xpad = (float*)d_ws;               // needs 268288 B of scratch
    float* out  = (float*)d_out;              // 65536 fp32
    dtw_pad_kernel<<<(XPAD_TOTAL + 255) / 256, 256, 0, stream>>>(x, xpad);
    dtw_main<<<1, 256, 0, stream>>>(xpad, k, out);
}